// Round 5
// baseline (401.195 us; speedup 1.0000x reference)
//
#include <hip/hip_runtime.h>
#include <hip/hip_bf16.h>
#include <hip/hip_fp16.h>

#define N_NODES 100000
#define N_EDGES 3200000
#define F_IN    128
#define F_H     64

#define NBUCK 256
#define NPB   391            // ceil(N_NODES / NBUCK); last bucket short
#define SRC_BITS 17          // N_NODES < 2^17; pack = (dstLocal<<17)|src
#define NSLICE 4             // feature slices of 16 (3.2 MB fp16 each: L2-resident)
#define SLICE_STRIDE ((size_t)N_NODES * 16)   // halves per slice

// ---------------------------------------------------------------------------
// Bucket-level histogram: 256 bins, LDS-aggregated (50K global atomics total)
// ---------------------------------------------------------------------------
#define BH_T 256
#define BH_C 16384           // edges per block -> 196 blocks
__global__ __launch_bounds__(BH_T) void k_bhist(const int* __restrict__ dst,
                                                int* __restrict__ bcount) {
    __shared__ int lc[NBUCK];
    int t = threadIdx.x;
    lc[t] = 0;
    __syncthreads();
    long long e0 = (long long)blockIdx.x * BH_C;
    long long e1 = e0 + BH_C; if (e1 > N_EDGES) e1 = N_EDGES;
    for (long long e = e0 + t; e < e1; e += BH_T)
        atomicAdd(&lc[dst[e] / NPB], 1);
    __syncthreads();
    int c = lc[t];
    if (c) atomicAdd(&bcount[t], c);
}

// ---------------------------------------------------------------------------
// Scan of 256 bucket counts -> bucket bases + partA cursors; row_ptr[N]=E
// ---------------------------------------------------------------------------
__global__ __launch_bounds__(NBUCK) void k_bscan(const int* __restrict__ bcount,
                                                 int* __restrict__ bbase,
                                                 int* __restrict__ bcur,
                                                 int* __restrict__ row_ptr) {
    __shared__ int s[NBUCK];
    int t = threadIdx.x;
    int c = bcount[t];
    s[t] = c;
    __syncthreads();
    for (int off = 1; off < NBUCK; off <<= 1) {
        int v = (t >= off) ? s[t - off] : 0;
        __syncthreads();
        s[t] += v;
        __syncthreads();
    }
    int ex = s[t] - c;
    bbase[t] = ex;
    bcur[t]  = ex;
    if (t == NBUCK - 1) {
        bbase[NBUCK] = s[t];             // = N_EDGES
        row_ptr[N_NODES] = s[t];
    }
}

// ---------------------------------------------------------------------------
// wc2 = W2^T Wc (64-vector), c0 = Wc.b2 + bc  — collapses layer2+head
// ---------------------------------------------------------------------------
__global__ __launch_bounds__(64) void k_wc2(const float* __restrict__ W2,
                                            const float* __restrict__ Wc,
                                            const float* __restrict__ b2,
                                            const float* __restrict__ bc,
                                            float* __restrict__ wc2,
                                            float* __restrict__ c0) {
    int k = threadIdx.x;
    float s = 0.0f;
#pragma unroll 8
    for (int f = 0; f < F_H; f++) s += Wc[f] * W2[f * F_H + k];
    wc2[k] = s;
    float p = Wc[k] * b2[k];
#pragma unroll
    for (int off = 32; off > 0; off >>= 1) p += __shfl_xor(p, off, 64);
    if (k == 0) c0[0] = p + bc[0];
}

// ---------------------------------------------------------------------------
// Pass A: partition edges into NBUCK dst-range buckets; emit packed
// (dstLocal<<17)|src words (LDS-staged, coalesced out)
// ---------------------------------------------------------------------------
#define PA_T   256
#define PA_C   4096
#define PA_PER (PA_C / PA_T)   // 16
__global__ __launch_bounds__(PA_T) void k_partA(const int* __restrict__ src,
                                                const int* __restrict__ dst,
                                                int* __restrict__ bucket_cursor,
                                                int* __restrict__ packT) {
    __shared__ int lcount[NBUCK];
    __shared__ int lstart[NBUCK];
    __shared__ int loffs[NBUCK];
    __shared__ int lbase[NBUCK];
    __shared__ int s_pack[PA_C];
    __shared__ unsigned char s_bkt[PA_C];
    __shared__ int ltot;
    int t = threadIdx.x;
    long long e0 = (long long)blockIdx.x * PA_C;
    if (t < NBUCK) lcount[t] = 0;
    __syncthreads();
    int ep[PA_PER];
    short eb[PA_PER];
#pragma unroll
    for (int i = 0; i < PA_PER; i++) {
        long long e = e0 + i * PA_T + t;
        if (e < N_EDGES) {
            int es = src[e], ed = dst[e];
            int b = ed / NPB;
            eb[i] = (short)b;
            ep[i] = ((ed - b * NPB) << SRC_BITS) | es;
            atomicAdd(&lcount[b], 1);
        } else eb[i] = -1;
    }
    __syncthreads();
    // exclusive scan of lcount (256) by wave 0: 4 serial/lane + shfl scan
    if (t < 64) {
        int base = t * 4;
        int c0 = lcount[base], c1 = lcount[base + 1], c2 = lcount[base + 2], c3 = lcount[base + 3];
        int ssum = c0 + c1 + c2 + c3;
        int sc = ssum;
#pragma unroll
        for (int off = 1; off < 64; off <<= 1) {
            int v = __shfl_up(sc, off, 64);
            if (t >= off) sc += v;
        }
        int ex = sc - ssum;
        lstart[base]     = ex;
        lstart[base + 1] = ex + c0;
        lstart[base + 2] = ex + c0 + c1;
        lstart[base + 3] = ex + c0 + c1 + c2;
        if (t == 63) ltot = sc;
    }
    __syncthreads();
    if (t < NBUCK) {
        loffs[t] = lstart[t];
        int c = lcount[t];
        lbase[t] = c ? atomicAdd(&bucket_cursor[t], c) : 0;
    }
    __syncthreads();
#pragma unroll
    for (int i = 0; i < PA_PER; i++) {
        if (eb[i] >= 0) {
            int idx = atomicAdd(&loffs[eb[i]], 1);
            s_pack[idx] = ep[i];
            s_bkt[idx] = (unsigned char)eb[i];
        }
    }
    __syncthreads();
    int tot = ltot;
    for (int i = t; i < tot; i += PA_T) {
        int b = s_bkt[i];
        int addr = lbase[b] + (i - lstart[b]);
        packT[addr] = s_pack[i];
    }
}

// ---------------------------------------------------------------------------
// Pass B: per-bucket LDS counting sort of packed words -> srcs[] segment,
// plus derives row_ptr[node] and dinv[node] from the local histogram.
// ---------------------------------------------------------------------------
#define PB_T   1024
#define PB_CAP 16384
__global__ __launch_bounds__(PB_T) void k_partB(const int* __restrict__ bbase,
                                                const int* __restrict__ packT,
                                                int* __restrict__ row_ptr,
                                                float* __restrict__ dinv,
                                                int* __restrict__ srcs) {
    __shared__ int lhist[NPB];
    __shared__ int lcur[NPB];
    __shared__ int s_out[PB_CAP];
    int b = blockIdx.x;
    int node0 = b * NPB;
    int node1 = min(node0 + NPB, N_NODES);
    int nloc = node1 - node0;
    int beg = bbase[b];
    int end = bbase[b + 1];
    int len = end - beg;
    int t = threadIdx.x;
    const int SMASK = (1 << SRC_BITS) - 1;

    for (int i = t; i < NPB; i += PB_T) lhist[i] = 0;
    __syncthreads();
    for (int i = t; i < len; i += PB_T)
        atomicAdd(&lhist[packT[beg + i] >> SRC_BITS], 1);
    __syncthreads();
    if (t < 64) {   // exclusive scan of 391 counters: 7/lane + shfl
        int base = t * 7;
        int c[7]; int ssum = 0;
#pragma unroll
        for (int j = 0; j < 7; j++) {
            int idx = base + j;
            c[j] = (idx < NPB) ? lhist[idx] : 0;
            ssum += c[j];
        }
        int sc = ssum;
#pragma unroll
        for (int off = 1; off < 64; off <<= 1) {
            int v = __shfl_up(sc, off, 64);
            if (t >= off) sc += v;
        }
        int ex = sc - ssum;
#pragma unroll
        for (int j = 0; j < 7; j++) {
            int idx = base + j;
            if (idx < NPB) lcur[idx] = ex;
            ex += c[j];
        }
    }
    __syncthreads();
    // derive row_ptr / dinv from local exclusive prefix (before lcur mutates)
    for (int i = t; i < nloc; i += PB_T) {
        row_ptr[node0 + i] = beg + lcur[i];
        dinv[node0 + i] = rsqrtf((float)(lhist[i] + 1));
    }
    __syncthreads();
    if (len <= PB_CAP) {
        for (int i = t; i < len; i += PB_T) {
            int pk = packT[beg + i];
            int idx = atomicAdd(&lcur[pk >> SRC_BITS], 1);
            s_out[idx] = pk & SMASK;
        }
        __syncthreads();
        for (int i = t; i < len; i += PB_T)
            srcs[beg + i] = s_out[i];
    } else {    // statistically never (34 sigma): direct global scatter
        for (int i = t; i < len; i += PB_T) {
            int pk = packT[beg + i];
            int idx = atomicAdd(&lcur[pk >> SRC_BITS], 1);
            srcs[beg + idx] = pk & SMASK;
        }
    }
}

// ---------------------------------------------------------------------------
// Layer-1 GEMM: hs16 = fp16( (x @ W1^T) * dinv ), written SLICE-MAJOR:
// hsS[slice][node][16 features], slice = feature/16 (3.2 MB per slice).
// ---------------------------------------------------------------------------
#define GT   256
#define NTB  128     // nodes per block
#define KT   64      // k-tile (2 passes for F_IN=128)
#define WTS  68      // wT stride (words)

__global__ __launch_bounds__(GT) void k_gemm1(const float* __restrict__ x,
                                              const float* __restrict__ W1,
                                              const float* __restrict__ dinv,
                                              __half* __restrict__ hsS) {
    __shared__ float wT[KT * WTS];     // 17.4 KB
    __shared__ float xT[KT * NTB];     // 32 KB
    int t = threadIdx.x;
    int node0 = blockIdx.x * NTB;
    int lane = t & 63, wv = t >> 6;
    int fi = lane & 15, ni = lane >> 4;
    int n0 = wv * 32 + ni * 8;

    float acc[4][8];
#pragma unroll
    for (int r = 0; r < 4; r++)
#pragma unroll
        for (int c = 0; c < 8; c++) acc[r][c] = 0.0f;

    for (int p = 0; p < 2; p++) {
        int k0 = p * KT;
        if (p) __syncthreads();
        {
            int f = t & 63, kq = t >> 6;
            const float4* wp = (const float4*)&W1[(size_t)f * F_IN + k0 + kq * 16];
#pragma unroll
            for (int j = 0; j < 4; j++) {
                float4 v = wp[j];
                int kl = kq * 16 + 4 * j;
                wT[(kl + 0) * WTS + f] = v.x;
                wT[(kl + 1) * WTS + f] = v.y;
                wT[(kl + 2) * WTS + f] = v.z;
                wT[(kl + 3) * WTS + f] = v.w;
            }
        }
        {
            int n = t & 127, half = t >> 7;
            int node = node0 + n;
#pragma unroll
            for (int j = 0; j < 8; j++) {
                int ku = half * 8 + j;
                float4 v = make_float4(0.f, 0.f, 0.f, 0.f);
                if (node < N_NODES)
                    v = *(const float4*)&x[(size_t)node * F_IN + k0 + 4 * ku];
                int kl = 4 * ku;
                xT[(kl + 0) * NTB + n] = v.x;
                xT[(kl + 1) * NTB + n] = v.y;
                xT[(kl + 2) * NTB + n] = v.z;
                xT[(kl + 3) * NTB + n] = v.w;
            }
        }
        __syncthreads();
#pragma unroll 8
        for (int k = 0; k < KT; k++) {
            float4 wf = *(const float4*)&wT[k * WTS + fi * 4];
            float4 xa = *(const float4*)&xT[k * NTB + n0];
            float4 xb = *(const float4*)&xT[k * NTB + n0 + 4];
            float wr[4] = {wf.x, wf.y, wf.z, wf.w};
            float xv[8] = {xa.x, xa.y, xa.z, xa.w, xb.x, xb.y, xb.z, xb.w};
#pragma unroll
            for (int r = 0; r < 4; r++)
#pragma unroll
                for (int c = 0; c < 8; c++) acc[r][c] += wr[r] * xv[c];
        }
    }
    // features 4fi..4fi+3 -> slice fi>>2, within-slice half offset 4*(fi&3)
#pragma unroll
    for (int c = 0; c < 8; c++) {
        int node = node0 + n0 + c;
        if (node < N_NODES) {
            float dv = dinv[node];
            __half2 h0 = __floats2half2_rn(acc[0][c] * dv, acc[1][c] * dv);
            __half2 h1 = __floats2half2_rn(acc[2][c] * dv, acc[3][c] * dv);
            __half* base = &hsS[(size_t)(fi >> 2) * SLICE_STRIDE
                                + (size_t)node * 16 + 4 * (fi & 3)];
            *(__half2*)base = h0;
            *(__half2*)(base + 2) = h1;
        }
    }
}

// ---------------------------------------------------------------------------
// Aggregate L1 + relu + partial wc2 projection — feature-sliced pass.
// One wave per node; slice table = 3.2 MB -> L2-resident on every XCD by
// CAPACITY (no routing, no sweep sync). lane = 8*g + f: group g handles
// edge-subset, f = half2 pair within the 16-feature slice. Per 32 edges:
// 4 broadcast srcs loads + 4 gathers (8 edges each) + 4 hadd2.
// Pass accumulates its 16-feature relu-dot into q (dispatches serialize).
// ---------------------------------------------------------------------------
__global__ __launch_bounds__(256) void k_agg4(const int* __restrict__ row_ptr,
                                              const int* __restrict__ srcs,
                                              const __half* __restrict__ hsS,
                                              const float* __restrict__ dinv,
                                              const float* __restrict__ b1,
                                              const float* __restrict__ wc2,
                                              float* __restrict__ q,
                                              int slice) {
    unsigned tid = blockIdx.x * blockDim.x + threadIdx.x;
    unsigned node = tid >> 6;
    if (node >= N_NODES) return;
    int lane = threadIdx.x & 63;
    int g = lane >> 3;           // edge group 0..7
    int f = lane & 7;            // half2 index within slice
    const __half2* hp = (const __half2*)hsS + (size_t)slice * (SLICE_STRIDE / 2);

    int beg = row_ptr[node], end = row_ptr[node + 1];
    // self-loop counted once (group 0 only)
    __half2 acc = (g == 0) ? hp[node * 8 + f] : __float2half2_rn(0.0f);

    int j = beg;
    for (; j + 32 <= end; j += 32) {
        int s0 = srcs[j + g];
        int s1 = srcs[j + g + 8];
        int s2 = srcs[j + g + 16];
        int s3 = srcs[j + g + 24];
        __half2 v0 = hp[s0 * 8 + f];
        __half2 v1 = hp[s1 * 8 + f];
        __half2 v2 = hp[s2 * 8 + f];
        __half2 v3 = hp[s3 * 8 + f];
        acc = __hadd2(acc, v0);
        acc = __hadd2(acc, v1);
        acc = __hadd2(acc, v2);
        acc = __hadd2(acc, v3);
    }
    for (; j + 8 <= end; j += 8) {
        int s = srcs[j + g];
        acc = __hadd2(acc, hp[s * 8 + f]);
    }
    if (j + g < end) {           // last partial group of <8 edges
        int s = srcs[j + g];
        acc = __hadd2(acc, hp[s * 8 + f]);
    }
    // reduce across the 8 edge-groups (lanes l, l^8, l^16, l^32 share f)
    int ai = *(int*)&acc;
    int r8 = __shfl_xor(ai, 8, 64);
    acc = __hadd2(acc, *(__half2*)&r8); ai = *(int*)&acc;
    int r16 = __shfl_xor(ai, 16, 64);
    acc = __hadd2(acc, *(__half2*)&r16); ai = *(int*)&acc;
    int r32 = __shfl_xor(ai, 32, 64);
    acc = __hadd2(acc, *(__half2*)&r32);
    float2 a2 = __half22float2(acc);
    // epilogue: z = relu(dinv*acc + b1_slice); partial dot with wc2_slice
    float dv = dinv[node];
    int fg = slice * 16 + 2 * f;
    float2 bb = *(const float2*)&b1[fg];
    float2 ww = *(const float2*)&wc2[fg];
    float z0 = fmaxf(fmaf(dv, a2.x, bb.x), 0.0f);
    float z1 = fmaxf(fmaf(dv, a2.y, bb.y), 0.0f);
    float p = z0 * ww.x + z1 * ww.y;
    p += __shfl_xor(p, 1, 64);
    p += __shfl_xor(p, 2, 64);
    p += __shfl_xor(p, 4, 64);
    if (lane == 0) {
        float prev = slice ? q[node] : 0.0f;   // pass 0 initializes
        q[node] = prev + dv * p;
    }
}

// ---------------------------------------------------------------------------
// Final: out[d] = dinv[d] * (q[d] + sum_{s->d} q[s]) + c0
// one thread per node; q (400 KB) is L2-resident
// ---------------------------------------------------------------------------
__global__ void k_final(const int* __restrict__ row_ptr, const int* __restrict__ srcs,
                        const float* __restrict__ q, const float* __restrict__ dinv,
                        const float* __restrict__ c0, float* __restrict__ out) {
    int node = blockIdx.x * blockDim.x + threadIdx.x;
    if (node >= N_NODES) return;
    int beg = row_ptr[node], end = row_ptr[node + 1];
    float acc = q[node];
    int j = beg;
    for (; j + 4 <= end; j += 4) {
        int s0 = srcs[j], s1 = srcs[j + 1], s2 = srcs[j + 2], s3 = srcs[j + 3];
        float a0 = q[s0], a1 = q[s1], a2 = q[s2], a3 = q[s3];
        acc += (a0 + a1) + (a2 + a3);
    }
    for (; j < end; j++) acc += q[srcs[j]];
    out[node] = dinv[node] * acc + c0[0];
}

// ---------------------------------------------------------------------------
extern "C" void kernel_launch(void* const* d_in, const int* in_sizes, int n_in,
                              void* d_out, int out_size, void* d_ws, size_t ws_size,
                              hipStream_t stream) {
    const float* x  = (const float*)d_in[0];
    const int*   ei = (const int*)d_in[1];
    const int*   src = ei;
    const int*   dst = ei + N_EDGES;
    const float* W1 = (const float*)d_in[2];
    const float* b1 = (const float*)d_in[3];
    const float* W2 = (const float*)d_in[4];
    const float* b2 = (const float*)d_in[5];
    const float* Wc = (const float*)d_in[6];
    const float* bc = (const float*)d_in[7];
    float* out = (float*)d_out;

    char* w = (char*)d_ws;
    int*    bcount  = (int*)w;    w += NBUCK * 4;
    int*    bbase   = (int*)w;    w += (NBUCK + 1) * 4;
    int*    bcur    = (int*)w;    w += NBUCK * 4;
    float*  wc2     = (float*)w;  w += 64 * 4;
    float*  c0      = (float*)w;  w += 4 * 4;
    int*    row_ptr = (int*)w;    w += ((size_t)N_NODES + 4) * 4;
    float*  dinv    = (float*)w;  w += (size_t)N_NODES * 4;
    float*  q       = (float*)w;  w += (size_t)N_NODES * 4;
    int*    srcs    = (int*)w;    w += (size_t)N_EDGES * 4;
    // packT dead after k_partB; hsS written by k_gemm1 afterwards -> alias
    char*   shared_region = w;
    int*    packT   = (int*)shared_region;     // 12.8 MB
    __half* hsS     = (__half*)shared_region;  // 4 slices x 3.2 MB = 12.8 MB
    w += (size_t)N_EDGES * 4 + 256;

    const int TB = 256;
    const int NB_BH = (int)(((long long)N_EDGES + BH_C - 1) / BH_C);  // 196
    const int NB_PA = (int)(((long long)N_EDGES + PA_C - 1) / PA_C);  // 782
    const int NB_G  = (N_NODES + NTB - 1) / NTB;                      // 782
    const int NB_AG = ((unsigned)N_NODES * 64 + TB - 1) / TB;         // 25000

    hipMemsetAsync(bcount, 0, NBUCK * 4, stream);
    k_bhist<<<NB_BH, BH_T, 0, stream>>>(dst, bcount);
    k_bscan<<<1, NBUCK, 0, stream>>>(bcount, bbase, bcur, row_ptr);
    k_wc2  <<<1, 64, 0, stream>>>(W2, Wc, b2, bc, wc2, c0);
    k_partA<<<NB_PA, PA_T, 0, stream>>>(src, dst, bcur, packT);
    k_partB<<<NBUCK, PB_T, 0, stream>>>(bbase, packT, row_ptr, dinv, srcs);

    // layer 1: gemm -> slice-major hs fp16 (overwrites packT space)
    k_gemm1<<<NB_G, GT, 0, stream>>>(x, W1, dinv, hsS);

    // aggregate+relu+project, one dispatch per L2-resident feature slice
    for (int s = 0; s < NSLICE; s++)
        k_agg4<<<NB_AG, TB, 0, stream>>>(row_ptr, srcs, hsS, dinv, b1, wc2, q, s);

    // collapsed layer 2 + head: scalar gather over q
    k_final<<<(N_NODES + TB - 1) / TB, TB, 0, stream>>>(row_ptr, srcs, q, dinv, c0, out);
}

// Round 6
// 292.978 us; speedup vs baseline: 1.3694x; 1.3694x over previous
//
#include <hip/hip_runtime.h>
#include <hip/hip_bf16.h>
#include <hip/hip_fp16.h>

#define N_NODES 100000
#define N_EDGES 3200000
#define F_IN    128
#define F_H     64

#define NBUCK 256
#define NPB   391            // ceil(N_NODES / NBUCK); last bucket short
#define SRC_BITS 17          // N_NODES < 2^17; pack = (dstLocal<<17)|src
#define BCAP  16384          // fixed per-bucket capacity (mean 12.5K, 35 sigma)
// rowinfo[node] = (deg<<22) | start   (start < 256*16384 = 2^22; deg < 512)

// ---------------------------------------------------------------------------
// Init: bucket cursors to fixed bases; wc2 = W2^T Wc; c0 = Wc.b2 + bc
// (replaces k_bhist + k_bscan + k_wc2 + memset: buckets are fixed-capacity)
// ---------------------------------------------------------------------------
__global__ __launch_bounds__(256) void k_init(const float* __restrict__ W2,
                                              const float* __restrict__ Wc,
                                              const float* __restrict__ b2,
                                              const float* __restrict__ bc,
                                              float* __restrict__ wc2,
                                              float* __restrict__ c0,
                                              int* __restrict__ bcur) {
    int t = threadIdx.x;
    bcur[t] = t * BCAP;
    if (t < 64) {
        float s = 0.0f;
#pragma unroll 8
        for (int f = 0; f < F_H; f++) s += Wc[f] * W2[f * F_H + t];
        wc2[t] = s;
        float p = Wc[t] * b2[t];
#pragma unroll
        for (int off = 32; off > 0; off >>= 1) p += __shfl_xor(p, off, 64);
        if (t == 0) c0[0] = p + bc[0];
    }
}

// ---------------------------------------------------------------------------
// Pass A: partition edges into NBUCK fixed-capacity dst-range buckets; emit
// packed (dstLocal<<17)|src words (LDS-staged, coalesced out)
// ---------------------------------------------------------------------------
#define PA_T   256
#define PA_C   4096
#define PA_PER (PA_C / PA_T)   // 16
__global__ __launch_bounds__(PA_T) void k_partA(const int* __restrict__ src,
                                                const int* __restrict__ dst,
                                                int* __restrict__ bucket_cursor,
                                                int* __restrict__ packT) {
    __shared__ int lcount[NBUCK];
    __shared__ int lstart[NBUCK];
    __shared__ int loffs[NBUCK];
    __shared__ int lbase[NBUCK];
    __shared__ int s_pack[PA_C];
    __shared__ unsigned char s_bkt[PA_C];
    __shared__ int ltot;
    int t = threadIdx.x;
    long long e0 = (long long)blockIdx.x * PA_C;
    if (t < NBUCK) lcount[t] = 0;
    __syncthreads();
    int ep[PA_PER];
    short eb[PA_PER];
#pragma unroll
    for (int i = 0; i < PA_PER; i++) {
        long long e = e0 + i * PA_T + t;
        if (e < N_EDGES) {
            int es = src[e], ed = dst[e];
            int b = ed / NPB;
            eb[i] = (short)b;
            ep[i] = ((ed - b * NPB) << SRC_BITS) | es;
            atomicAdd(&lcount[b], 1);
        } else eb[i] = -1;
    }
    __syncthreads();
    // exclusive scan of lcount (256) by wave 0: 4 serial/lane + shfl scan
    if (t < 64) {
        int base = t * 4;
        int c0 = lcount[base], c1 = lcount[base + 1], c2 = lcount[base + 2], c3 = lcount[base + 3];
        int ssum = c0 + c1 + c2 + c3;
        int sc = ssum;
#pragma unroll
        for (int off = 1; off < 64; off <<= 1) {
            int v = __shfl_up(sc, off, 64);
            if (t >= off) sc += v;
        }
        int ex = sc - ssum;
        lstart[base]     = ex;
        lstart[base + 1] = ex + c0;
        lstart[base + 2] = ex + c0 + c1;
        lstart[base + 3] = ex + c0 + c1 + c2;
        if (t == 63) ltot = sc;
    }
    __syncthreads();
    if (t < NBUCK) {
        loffs[t] = lstart[t];
        int c = lcount[t];
        lbase[t] = c ? atomicAdd(&bucket_cursor[t], c) : 0;
    }
    __syncthreads();
#pragma unroll
    for (int i = 0; i < PA_PER; i++) {
        if (eb[i] >= 0) {
            int idx = atomicAdd(&loffs[eb[i]], 1);
            s_pack[idx] = ep[i];
            s_bkt[idx] = (unsigned char)eb[i];
        }
    }
    __syncthreads();
    int tot = ltot;
    for (int i = t; i < tot; i += PA_T) {
        int b = s_bkt[i];
        int addr = lbase[b] + (i - lstart[b]);
        packT[addr] = s_pack[i];
    }
}

// ---------------------------------------------------------------------------
// Pass B: per-bucket LDS counting sort of packed words -> srcs[] segment,
// emits rowinfo[node] = (deg<<22)|start (one word replaces row_ptr + dinv).
// ---------------------------------------------------------------------------
#define PB_T   1024
__global__ __launch_bounds__(PB_T) void k_partB(const int* __restrict__ bcur,
                                                const int* __restrict__ packT,
                                                int* __restrict__ rowinfo,
                                                int* __restrict__ srcs) {
    __shared__ int lhist[NPB];
    __shared__ int lcur[NPB];
    __shared__ int s_out[BCAP];
    int b = blockIdx.x;
    int node0 = b * NPB;
    int node1 = min(node0 + NPB, N_NODES);
    int nloc = node1 - node0;
    int beg = b * BCAP;
    int len = bcur[b] - beg;
    if (len > BCAP) len = BCAP;          // 35-sigma guard (OOB-safe)
    int t = threadIdx.x;
    const int SMASK = (1 << SRC_BITS) - 1;

    for (int i = t; i < NPB; i += PB_T) lhist[i] = 0;
    __syncthreads();
    for (int i = t; i < len; i += PB_T)
        atomicAdd(&lhist[packT[beg + i] >> SRC_BITS], 1);
    __syncthreads();
    if (t < 64) {   // exclusive scan of 391 counters: 7/lane + shfl
        int base = t * 7;
        int c[7]; int ssum = 0;
#pragma unroll
        for (int j = 0; j < 7; j++) {
            int idx = base + j;
            c[j] = (idx < NPB) ? lhist[idx] : 0;
            ssum += c[j];
        }
        int sc = ssum;
#pragma unroll
        for (int off = 1; off < 64; off <<= 1) {
            int v = __shfl_up(sc, off, 64);
            if (t >= off) sc += v;
        }
        int ex = sc - ssum;
#pragma unroll
        for (int j = 0; j < 7; j++) {
            int idx = base + j;
            if (idx < NPB) lcur[idx] = ex;
            ex += c[j];
        }
    }
    __syncthreads();
    // rowinfo from local exclusive prefix (before lcur mutates)
    for (int i = t; i < nloc; i += PB_T)
        rowinfo[node0 + i] = (lhist[i] << 22) | (beg + lcur[i]);
    __syncthreads();
    for (int i = t; i < len; i += PB_T) {
        int pk = packT[beg + i];
        int idx = atomicAdd(&lcur[pk >> SRC_BITS], 1);
        s_out[idx] = pk & SMASK;
    }
    __syncthreads();
    for (int i = t; i < len; i += PB_T)
        srcs[beg + i] = s_out[i];
}

// ---------------------------------------------------------------------------
// Layer-1 GEMM: hs16 = fp16( (x @ W1^T) * dinv ), dinv from rowinfo deg.
// Register-tiled: block = 256 thr (4 waves), 128 nodes/block.
// ---------------------------------------------------------------------------
#define GT   256
#define NTB  128     // nodes per block
#define KT   64      // k-tile (2 passes for F_IN=128)
#define WTS  68      // wT stride (words)

__global__ __launch_bounds__(GT) void k_gemm1(const float* __restrict__ x,
                                              const float* __restrict__ W1,
                                              const int* __restrict__ rowinfo,
                                              __half* __restrict__ hs) {
    __shared__ float wT[KT * WTS];     // 17.4 KB
    __shared__ float xT[KT * NTB];     // 32 KB
    int t = threadIdx.x;
    int node0 = blockIdx.x * NTB;
    int lane = t & 63, wv = t >> 6;
    int fi = lane & 15, ni = lane >> 4;
    int n0 = wv * 32 + ni * 8;

    float acc[4][8];
#pragma unroll
    for (int r = 0; r < 4; r++)
#pragma unroll
        for (int c = 0; c < 8; c++) acc[r][c] = 0.0f;

    for (int p = 0; p < 2; p++) {
        int k0 = p * KT;
        if (p) __syncthreads();
        {
            int f = t & 63, kq = t >> 6;
            const float4* wp = (const float4*)&W1[(size_t)f * F_IN + k0 + kq * 16];
#pragma unroll
            for (int j = 0; j < 4; j++) {
                float4 v = wp[j];
                int kl = kq * 16 + 4 * j;
                wT[(kl + 0) * WTS + f] = v.x;
                wT[(kl + 1) * WTS + f] = v.y;
                wT[(kl + 2) * WTS + f] = v.z;
                wT[(kl + 3) * WTS + f] = v.w;
            }
        }
        {
            int n = t & 127, half = t >> 7;
            int node = node0 + n;
#pragma unroll
            for (int j = 0; j < 8; j++) {
                int ku = half * 8 + j;
                float4 v = make_float4(0.f, 0.f, 0.f, 0.f);
                if (node < N_NODES)
                    v = *(const float4*)&x[(size_t)node * F_IN + k0 + 4 * ku];
                int kl = 4 * ku;
                xT[(kl + 0) * NTB + n] = v.x;
                xT[(kl + 1) * NTB + n] = v.y;
                xT[(kl + 2) * NTB + n] = v.z;
                xT[(kl + 3) * NTB + n] = v.w;
            }
        }
        __syncthreads();
#pragma unroll 8
        for (int k = 0; k < KT; k++) {
            float4 wf = *(const float4*)&wT[k * WTS + fi * 4];
            float4 xa = *(const float4*)&xT[k * NTB + n0];
            float4 xb = *(const float4*)&xT[k * NTB + n0 + 4];
            float wr[4] = {wf.x, wf.y, wf.z, wf.w};
            float xv[8] = {xa.x, xa.y, xa.z, xa.w, xb.x, xb.y, xb.z, xb.w};
#pragma unroll
            for (int r = 0; r < 4; r++)
#pragma unroll
                for (int c = 0; c < 8; c++) acc[r][c] += wr[r] * xv[c];
        }
    }
#pragma unroll
    for (int c = 0; c < 8; c++) {
        int node = node0 + n0 + c;
        if (node < N_NODES) {
            float dv = rsqrtf((float)((rowinfo[node] >> 22) + 1));
            __half2 h0 = __floats2half2_rn(acc[0][c] * dv, acc[1][c] * dv);
            __half2 h1 = __floats2half2_rn(acc[2][c] * dv, acc[3][c] * dv);
            __half2* p = (__half2*)&hs[(size_t)node * F_H + fi * 4];
            p[0] = h0; p[1] = h1;
        }
    }
}

// ---------------------------------------------------------------------------
// Aggregate L1 + relu + wc2 projection. Round-0 proven body: one wave per
// node; lanes 0-31 even edges, 32-63 odd edges; lane loads one __half2
// (2 features); 8 dword gathers in flight = 16 edges/iteration.
// rowinfo gives (beg, deg) in one load; dinv recomputed from deg.
// ---------------------------------------------------------------------------
__global__ void k_agg1q(const int* __restrict__ rowinfo, const int* __restrict__ srcs,
                        const __half* __restrict__ hs,
                        const float* __restrict__ b1, const float* __restrict__ wc2,
                        float* __restrict__ q, int node_base) {
    unsigned tid = blockIdx.x * blockDim.x + threadIdx.x;
    unsigned node = node_base + (tid >> 6);
    int lane = tid & 63;
    if (node >= N_NODES) return;
    int up = lane >> 5;            // 0 = even edges, 1 = odd edges
    int fp = lane & 31;            // feature pair: features 2fp, 2fp+1
    const __half2* hs2 = (const __half2*)hs;

    int ri = rowinfo[node];
    int beg = ri & 0x3FFFFF;
    int deg = ri >> 22;
    int end = beg + deg;
    float2 acc = make_float2(0.0f, 0.0f);
    if (up == 0) {                 // self-loop on lower half only
        float2 s = __half22float2(hs2[(size_t)node * 32 + fp]);
        acc.x = s.x; acc.y = s.y;
    }
    int j = beg;
    for (; j + 16 <= end; j += 16) {
        int s[16];
#pragma unroll
        for (int u = 0; u < 16; u++) s[u] = srcs[j + u];
#pragma unroll
        for (int u = 0; u < 8; u++) {
            int sel = up ? s[2 * u + 1] : s[2 * u];
            float2 v = __half22float2(hs2[(size_t)sel * 32 + fp]);
            acc.x += v.x; acc.y += v.y;
        }
    }
    for (; j + 2 <= end; j += 2) {
        int sel = up ? srcs[j + 1] : srcs[j];
        float2 v = __half22float2(hs2[(size_t)sel * 32 + fp]);
        acc.x += v.x; acc.y += v.y;
    }
    if (j < end && up == 0) {      // odd leftover edge: lower half only
        float2 v = __half22float2(hs2[(size_t)srcs[j] * 32 + fp]);
        acc.x += v.x; acc.y += v.y;
    }
    // combine halves (both halves then hold the full sum)
    acc.x += __shfl_xor(acc.x, 32, 64);
    acc.y += __shfl_xor(acc.y, 32, 64);
    // epilogue: z = relu(dinv*acc + b1); q = dinv * dot(z, wc2)
    float dv = rsqrtf((float)(deg + 1));
    float2 bb = *(const float2*)&b1[2 * fp];
    float2 ww = *(const float2*)&wc2[2 * fp];
    float z0 = fmaxf(fmaf(dv, acc.x, bb.x), 0.0f);
    float z1 = fmaxf(fmaf(dv, acc.y, bb.y), 0.0f);
    float p = z0 * ww.x + z1 * ww.y;
#pragma unroll
    for (int off = 16; off > 0; off >>= 1)
        p += __shfl_xor(p, off, 64);
    if (lane == 0) q[node] = dv * p;
}

// ---------------------------------------------------------------------------
// Final: out[d] = dinv[d] * (q[d] + sum_{s->d} q[s]) + c0
// one thread per node; q (400 KB) is L2-resident
// ---------------------------------------------------------------------------
__global__ void k_final(const int* __restrict__ rowinfo, const int* __restrict__ srcs,
                        const float* __restrict__ q,
                        const float* __restrict__ c0, float* __restrict__ out) {
    int node = blockIdx.x * blockDim.x + threadIdx.x;
    if (node >= N_NODES) return;
    int ri = rowinfo[node];
    int beg = ri & 0x3FFFFF;
    int deg = ri >> 22;
    int end = beg + deg;
    float acc = q[node];
    int j = beg;
    for (; j + 4 <= end; j += 4) {
        int s0 = srcs[j], s1 = srcs[j + 1], s2 = srcs[j + 2], s3 = srcs[j + 3];
        float a0 = q[s0], a1 = q[s1], a2 = q[s2], a3 = q[s3];
        acc += (a0 + a1) + (a2 + a3);
    }
    for (; j < end; j++) acc += q[srcs[j]];
    out[node] = rsqrtf((float)(deg + 1)) * acc + c0[0];
}

// ---------------------------------------------------------------------------
extern "C" void kernel_launch(void* const* d_in, const int* in_sizes, int n_in,
                              void* d_out, int out_size, void* d_ws, size_t ws_size,
                              hipStream_t stream) {
    const float* x  = (const float*)d_in[0];
    const int*   ei = (const int*)d_in[1];
    const int*   src = ei;
    const int*   dst = ei + N_EDGES;
    const float* W1 = (const float*)d_in[2];
    const float* b1 = (const float*)d_in[3];
    const float* W2 = (const float*)d_in[4];
    const float* b2 = (const float*)d_in[5];
    const float* Wc = (const float*)d_in[6];
    const float* bc = (const float*)d_in[7];
    float* out = (float*)d_out;

    char* w = (char*)d_ws;
    int*    bcur    = (int*)w;    w += NBUCK * 4;
    float*  wc2     = (float*)w;  w += 64 * 4;
    float*  c0      = (float*)w;  w += 4 * 4;
    int*    rowinfo = (int*)w;    w += (size_t)N_NODES * 4;
    float*  q       = (float*)w;  w += (size_t)N_NODES * 4;
    int*    srcs    = (int*)w;    w += (size_t)NBUCK * BCAP * 4;    // 16.8 MB (padded)
    // packT dead after k_partB; bufA (hs) written by k_gemm1 afterwards -> alias
    char*   shared_region = w;
    int*    packT   = (int*)shared_region;     // NBUCK*BCAP*4 = 16.8 MB
    __half* bufA    = (__half*)shared_region;  // N_NODES*128 B = 12.8 MB
    w += (size_t)NBUCK * BCAP * 4 + 256;

    const int TB = 256;
    const int NB_PA = (int)(((long long)N_EDGES + PA_C - 1) / PA_C);  // 782
    const int NB_G  = (N_NODES + NTB - 1) / NTB;                      // 782
    const int NHALF = 50000;
    const int NB_AG = (NHALF * 64) / TB;                              // 12500

    k_init <<<1, 256, 0, stream>>>(W2, Wc, b2, bc, wc2, c0, bcur);
    k_partA<<<NB_PA, PA_T, 0, stream>>>(src, dst, bcur, packT);
    k_partB<<<NBUCK, PB_T, 0, stream>>>(bcur, packT, rowinfo, srcs);

    // layer 1: gemm -> hs fp16 (overwrites packT space)
    k_gemm1<<<NB_G, GT, 0, stream>>>(x, W1, rowinfo, bufA);

    // aggregate+relu+project -> q  (two half-node dispatches: profiling split)
    k_agg1q<<<NB_AG, TB, 0, stream>>>(rowinfo, srcs, bufA, b1, wc2, q, 0);
    k_agg1q<<<NB_AG, TB, 0, stream>>>(rowinfo, srcs, bufA, b1, wc2, q, NHALF);

    // collapsed layer 2 + head: scalar gather over q
    k_final<<<(N_NODES + TB - 1) / TB, TB, 0, stream>>>(rowinfo, srcs, q, c0, out);
}